// Round 4
// baseline (407.897 us; speedup 1.0000x reference)
//
#include <hip/hip_runtime.h>
#include <hip/hip_bf16.h>

// HypergraphGNN on MI355X (gfx950).
// B=4 P=8 N=E=2000 IN=16 HID=128 NL=3 MULT=4. All f32 inputs; internal bf16 MFMA.
//
// Round-4 structure: heavy GEMM now uses a 4-buffer LDS ring with depth-2
// prefetch and counted s_waitcnt vmcnt(8) + raw s_barrier (T3/T4): the
// barrier never drains in-flight prefetches; a load issued at step t is
// consumed at t+2 (~2 steps of latency cover for HBM misses).
// Ring-safety: STAGE at step t writes buf[(t+2)&3], last read at
// compute(t-2), which all waves completed before the preceding collective
// barrier. LDS = 4 x 16KB ring (+ Gs 32KB aliased) = 64KB -> 2 blocks/CU.
//
// LDS swizzle (rule #21): linear LDS dest for global_load_lds; global source
// chunk pre-swizzled; reads apply the same involution.

typedef __attribute__((ext_vector_type(8))) short bf16x8;
typedef __attribute__((ext_vector_type(4))) float f32x4;

#define GLL16(gp, lp) __builtin_amdgcn_global_load_lds(                      \
    (const __attribute__((address_space(1))) void*)(gp),                     \
    (__attribute__((address_space(3))) void*)(lp), 16, 0, 0)

__device__ __forceinline__ unsigned short f2bf(float v) {
  __hip_bfloat16 h = __float2bfloat16(v);
  return __builtin_bit_cast(unsigned short, h);
}
__device__ __forceinline__ float bf2f(unsigned short u) {
  unsigned int x = ((unsigned int)u) << 16;
  return __builtin_bit_cast(float, x);
}

// ---------------------------------------------------------------------------
// H f32 -> Hb (straight) + HTb (transposed), bf16, padded 2000->2048 w/ zeros
__global__ void convH_k(const float* __restrict__ H,
                        unsigned short* __restrict__ Hb,
                        unsigned short* __restrict__ HTb) {
  int b  = blockIdx.z;
  int n0 = blockIdx.y * 32, e0 = blockIdx.x * 32;
  __shared__ float t[32][33];
  int tx = threadIdx.x & 31, ty = threadIdx.x >> 5;
  for (int r = ty; r < 32; r += 8) {
    int n = n0 + r, e = e0 + tx;
    float v = (n < 2000 && e < 2000) ? H[((long)b * 2000 + n) * 2000 + e] : 0.f;
    t[r][tx] = v;
    Hb[((long)b * 2048 + n) * 2048 + e] = f2bf(v);
  }
  __syncthreads();
  for (int r = ty; r < 32; r += 8) {
    HTb[((long)b * 2048 + (e0 + r)) * 2048 + (n0 + tx)] = f2bf(t[tx][r]);
  }
}

// generic f32 [R][C] -> bf16 [C][R]
__global__ void transposeW_k(const float* __restrict__ src,
                             unsigned short* __restrict__ dst, int R, int C) {
  __shared__ float t[32][33];
  int c0 = blockIdx.x * 32, r0 = blockIdx.y * 32;
  int tx = threadIdx.x & 31, ty = threadIdx.x >> 5;
  for (int rr = ty; rr < 32; rr += 8) {
    int rI = r0 + rr, cI = c0 + tx;
    t[rr][tx] = (rI < R && cI < C) ? src[(long)rI * C + cI] : 0.f;
  }
  __syncthreads();
  for (int rr = ty; rr < 32; rr += 8) {
    int cO = c0 + rr, rO = r0 + tx;
    if (cO < C && rO < R) dst[(long)cO * R + rO] = f2bf(t[tx][rr]);
  }
}

// x0 = nf @ W_in  (K=16). Writes xb [bp][2048][128] and xTb [bp][128][2048].
__global__ void x0_k(const float* __restrict__ nf, const float* __restrict__ Win,
                     unsigned short* __restrict__ xb, unsigned short* __restrict__ xTb) {
  int bp = blockIdx.y, n = blockIdx.x, d = threadIdx.x;
  float v = 0.f;
  if (n < 2000) {
    const float* row = nf + ((long)bp * 2000 + n) * 16;
#pragma unroll
    for (int k = 0; k < 16; k++) v += row[k] * Win[k * 128 + d];
  }
  unsigned short bits = f2bf(v);
  xb[((long)bp * 2048 + n) * 128 + d]  = bits;
  xTb[((long)bp * 128 + d) * 2048 + n] = bits;
}

// wf = W2 @ Wdec  (512x128 @ 128 -> 512)
__global__ void wfuse_k(const float* __restrict__ W2, const float* __restrict__ Wdec,
                        float* __restrict__ wf) {
  int i = blockIdx.x * 256 + threadIdx.x;
  if (i < 512) {
    float s = 0.f;
#pragma unroll 8
    for (int j = 0; j < 128; j++) s += W2[i * 128 + j] * Wdec[j];
    wf[i] = s;
  }
}

// ---------------------------------------------------------------------------
// Fused heavy GEMM: acc = A[2048][K=2048] @ BT[128][K]^T per (m-block, bz),
// then out = relu(acc @ W), Wt[d_out][d_in] global. Writes Cn and/or Ct.
// Grid: 512 blocks 1-D, XCD-swizzled. 256 threads.
template <int WN, int WT>
__global__ __launch_bounds__(256) void gemm_fused(
    const unsigned short* __restrict__ A, int lda, long strideA, int aDiv,
    const unsigned short* __restrict__ BT, int ldbt, long strideBT,
    const unsigned short* __restrict__ Wt,
    unsigned short* __restrict__ Cn, int ldc, long strideCn,
    unsigned short* __restrict__ Ct, int ldct, long strideCt, int K) {
  // XCD-aware bijective decode: XCD c = wgid&7 owns orig range [c*64, c*64+64)
  int wgid = blockIdx.x;
  int orig = (wgid & 7) * 64 + (wgid >> 3);
  int mblk = orig & 15;
  int bz   = orig >> 4;
  A  += (long)(bz / aDiv) * strideA;
  BT += (long)bz * strideBT;
  int m0 = mblk * 128;

  // 64 KB LDS: 4-buffer ring, each 16KB = [As 4096 | Bs 4096] shorts.
  // Gs (32KB) aliases buffers 0-1 after the main loop.
  __shared__ unsigned short smem[32768];

  int tid  = threadIdx.x;
  int lane = tid & 63;
  int w    = tid >> 6;
  int wr   = w >> 1, wc = w & 1;
  int fr   = lane & 15;   // frag row (A) / col (B,C)
  int fg   = lane >> 4;   // k-chunk (inputs) / row-subgroup (C/D)

  // staging addressing: LDS slot = tid*16B (linear); global chunk swizzled
  int sr  = tid >> 2;
  int scs = ((tid & 3) ^ ((sr >> 1) & 3)) * 8;
  const unsigned short* Ag0 = A + (long)(m0 + sr) * lda + scs;
  const unsigned short* Ag1 = A + (long)(m0 + 64 + sr) * lda + scs;
  const unsigned short* Bg0 = BT + (long)sr * ldbt + scs;
  const unsigned short* Bg1 = BT + (long)(64 + sr) * ldbt + scs;

#define STAGE(sel, kel) do {                                                 \
    unsigned short* _d = smem + (sel) * 8192 + tid * 8;                      \
    GLL16(Ag0 + (kel), _d);                                                  \
    GLL16(Ag1 + (kel), _d + 2048);                                           \
    GLL16(Bg0 + (kel), _d + 4096);                                           \
    GLL16(Bg1 + (kel), _d + 6144);                                           \
  } while (0)

  f32x4 acc[4][4] = {};
  int cIdx = (fg ^ ((fr >> 1) & 3)) * 8;  // swizzled k-chunk offset on read

#define COMPUTE(sel) do {                                                    \
    const unsigned short* As_ = smem + (sel) * 8192;                         \
    const unsigned short* Bs_ = As_ + 4096;                                  \
    bf16x8 af[4], bfv[4];                                                    \
    _Pragma("unroll")                                                        \
    for (int m = 0; m < 4; m++)                                              \
      af[m] = *(const bf16x8*)&As_[(wr * 64 + m * 16 + fr) * 32 + cIdx];     \
    _Pragma("unroll")                                                        \
    for (int n = 0; n < 4; n++)                                              \
      bfv[n] = *(const bf16x8*)&Bs_[(wc * 64 + n * 16 + fr) * 32 + cIdx];    \
    _Pragma("unroll")                                                        \
    for (int m = 0; m < 4; m++)                                              \
      _Pragma("unroll")                                                      \
      for (int n = 0; n < 4; n++)                                            \
        acc[m][n] = __builtin_amdgcn_mfma_f32_16x16x32_bf16(af[m], bfv[n],   \
                                                            acc[m][n], 0, 0, 0); \
  } while (0)

  int nt = K >> 5;  // 64

  // prologue: fill depth-2 ring
  STAGE(0, 0);
  STAGE(1, 32);
  // main loop: stage t+2, wait for t's loads (vmcnt: 12 outstanding -> 8
  // leaves t+1,t+2 in flight), collective barrier, compute t.
  for (int t = 0; t < nt - 2; ++t) {
    STAGE((t + 2) & 3, (t + 2) * 32);
    asm volatile("s_waitcnt vmcnt(8)" ::: "memory");
    __builtin_amdgcn_s_barrier();
    COMPUTE(t & 3);
  }
  // epilogue: drain remaining two tiles
  asm volatile("s_waitcnt vmcnt(4)" ::: "memory");
  __builtin_amdgcn_s_barrier();
  COMPUTE((nt - 2) & 3);
  asm volatile("s_waitcnt vmcnt(0)" ::: "memory");
  __builtin_amdgcn_s_barrier();
  COMPUTE((nt - 1) & 3);
#undef STAGE
#undef COMPUTE
  __syncthreads();  // all reads of ring done before Gs aliases it

  // acc tile -> Gs bf16 row-major (swizzled); Gs aliases ring buffers 0-1.
  unsigned short* Gs = smem;
#pragma unroll
  for (int m = 0; m < 4; m++) {
#pragma unroll
    for (int n = 0; n < 4; n++) {
      int rowb = wr * 64 + m * 16 + fg * 4;
      int col  = wc * 64 + n * 16 + fr;
      int ch = col >> 3, ci = col & 7;
#pragma unroll
      for (int r = 0; r < 4; r++) {
        int row = rowb + r;
        Gs[row * 128 + ((ch ^ (row & 7)) * 8) + ci] = f2bf(acc[m][n][r]);
      }
    }
  }
  __syncthreads();

  // stage 2: out = relu(G @ W). A-op = Gs; B-op = Wt rows from global (L2-hot).
  f32x4 acc2[4][4] = {};
#pragma unroll
  for (int kk = 0; kk < 4; kk++) {
    bf16x8 a2[4], b2[4];
#pragma unroll
    for (int m = 0; m < 4; m++) {
      int row = wr * 64 + m * 16 + fr;
      int c = kk * 4 + fg;
      a2[m] = *(const bf16x8*)&Gs[row * 128 + ((c ^ (row & 7)) * 8)];
    }
#pragma unroll
    for (int n = 0; n < 4; n++) {
      int row = wc * 64 + n * 16 + fr;
      b2[n] = *(const bf16x8*)&Wt[row * 128 + (kk * 4 + fg) * 8];
    }
#pragma unroll
    for (int m = 0; m < 4; m++)
#pragma unroll
      for (int n = 0; n < 4; n++)
        acc2[m][n] = __builtin_amdgcn_mfma_f32_16x16x32_bf16(a2[m], b2[n], acc2[m][n], 0, 0, 0);
  }

  // epilogue: relu + write
#pragma unroll
  for (int m = 0; m < 4; m++) {
#pragma unroll
    for (int n = 0; n < 4; n++) {
      int rowb = m0 + wr * 64 + m * 16 + fg * 4;
      int col  = wc * 64 + n * 16 + fr;
      float v0 = fmaxf(acc2[m][n][0], 0.f), v1 = fmaxf(acc2[m][n][1], 0.f);
      float v2 = fmaxf(acc2[m][n][2], 0.f), v3 = fmaxf(acc2[m][n][3], 0.f);
      if (WN) {
        unsigned short* p = Cn + bz * strideCn + (long)rowb * ldc + col;
        p[0]       = f2bf(v0);
        p[ldc]     = f2bf(v1);
        p[2 * ldc] = f2bf(v2);
        p[3 * ldc] = f2bf(v3);
      }
      if (WT) {
        ushort4 pk;
        pk.x = f2bf(v0); pk.y = f2bf(v1); pk.z = f2bf(v2); pk.w = f2bf(v3);
        *(ushort4*)(Ct + bz * strideCt + (long)col * ldct + rowb) = pk;
      }
    }
  }
}

// ---------------------------------------------------------------------------
// Fused MLP: out[row] = 10*tanh( (sum_i relu(x@W1)[row][i]*wf[i]) / sqrt(128) )
__global__ __launch_bounds__(256) void mlp_k(
    const unsigned short* __restrict__ X,    // [65536][128] bf16 (padded rows)
    const unsigned short* __restrict__ W1T,  // [512][128] bf16
    const float* __restrict__ wf,            // [512]
    float* __restrict__ out) {
  __shared__ unsigned short Xs[128 * 128];
  __shared__ unsigned short Bs[128 * 128];
  __shared__ float rowacc[128];

  int tid  = threadIdx.x;
  int lane = tid & 63;
  int w    = tid >> 6, wr = w >> 1, wc = w & 1;
  int fr   = lane & 15, fg = lane >> 4;
  long m0  = (long)blockIdx.x * 128;

#pragma unroll
  for (int i = 0; i < 8; i++) {
    int s = i * 256 + tid;
    int r = s >> 4, c = (s & 15) ^ (r & 7);
    GLL16(X + (m0 + r) * 128 + c * 8, (unsigned short*)Xs + s * 8);
  }
  if (tid < 128) rowacc[tid] = 0.f;

  float rs[4][4] = {};

  for (int nb = 0; nb < 4; nb++) {
#pragma unroll
    for (int i = 0; i < 8; i++) {
      int s = i * 256 + tid;
      int r = s >> 4, c = (s & 15) ^ (r & 7);
      GLL16(W1T + (long)(nb * 128 + r) * 128 + c * 8, (unsigned short*)Bs + s * 8);
    }
    __syncthreads();

    f32x4 acc[4][4] = {};
#pragma unroll
    for (int kk = 0; kk < 4; kk++) {
      bf16x8 a2[4], b2[4];
#pragma unroll
      for (int m = 0; m < 4; m++) {
        int row = wr * 64 + m * 16 + fr;
        int c = kk * 4 + fg;
        a2[m] = *(const bf16x8*)&Xs[row * 128 + ((c ^ (row & 7)) * 8)];
      }
#pragma unroll
      for (int n = 0; n < 4; n++) {
        int row = wc * 64 + n * 16 + fr;
        int c = kk * 4 + fg;
        b2[n] = *(const bf16x8*)&Bs[row * 128 + ((c ^ (row & 7)) * 8)];
      }
#pragma unroll
      for (int m = 0; m < 4; m++)
#pragma unroll
        for (int n = 0; n < 4; n++)
          acc[m][n] = __builtin_amdgcn_mfma_f32_16x16x32_bf16(a2[m], b2[n], acc[m][n], 0, 0, 0);
    }

#pragma unroll
    for (int n = 0; n < 4; n++) {
      float wv = wf[nb * 128 + wc * 64 + n * 16 + fr];
#pragma unroll
      for (int m = 0; m < 4; m++)
#pragma unroll
        for (int r = 0; r < 4; r++)
          rs[m][r] += fmaxf(acc[m][n][r], 0.f) * wv;
    }
    __syncthreads();
  }

#pragma unroll
  for (int m = 0; m < 4; m++)
#pragma unroll
    for (int r = 0; r < 4; r++) {
      float v = rs[m][r];
      v += __shfl_xor(v, 1, 64);
      v += __shfl_xor(v, 2, 64);
      v += __shfl_xor(v, 4, 64);
      v += __shfl_xor(v, 8, 64);
      if (fr == 0) atomicAdd(&rowacc[wr * 64 + m * 16 + fg * 4 + r], v);
    }
  __syncthreads();

  if (tid < 128) {
    long row = m0 + tid;
    int bp = (int)(row >> 11), n = (int)(row & 2047);
    if (n < 2000)
      out[(long)bp * 2000 + n] = 10.f * tanhf(rowacc[tid] * 0.08838834764831843f);
  }
}

// ---------------------------------------------------------------------------
extern "C" void kernel_launch(void* const* d_in, const int* in_sizes, int n_in,
                              void* d_out, int out_size, void* d_ws, size_t ws_size,
                              hipStream_t stream) {
  const float* nf    = (const float*)d_in[0];
  const float* H     = (const float*)d_in[1];
  const float* Win   = (const float*)d_in[2];
  const float* edgeW = (const float*)d_in[3];
  const float* nodeW = (const float*)d_in[4];
  const float* W1    = (const float*)d_in[5];
  const float* W2    = (const float*)d_in[6];
  const float* Wdec  = (const float*)d_in[7];
  float* out = (float*)d_out;

  char* ws = (char*)d_ws;
  unsigned short* Hb   = (unsigned short*)(ws + 0);          // 33.55 MB
  unsigned short* HTb  = (unsigned short*)(ws + 33554432);   // 33.55 MB
  unsigned short* xb   = (unsigned short*)(ws + 67108864);   // 16.78 MB
  unsigned short* xTb  = (unsigned short*)(ws + 83886080);   // 16.78 MB
  unsigned short* eTb  = (unsigned short*)(ws + 100663296);  // 16.78 MB
  unsigned short* edgeWT = (unsigned short*)(ws + 117440512);
  unsigned short* nodeWT = (unsigned short*)(ws + 117538816);
  unsigned short* W1T    = (unsigned short*)(ws + 117637120);
  float*          wf     = (float*)(ws + 117768192);
  (void)ws_size; (void)in_sizes; (void)n_in; (void)out_size;

  // ---- input prep ----
  convH_k<<<dim3(64, 64, 4), 256, 0, stream>>>(H, Hb, HTb);
  for (int l = 0; l < 3; l++) {
    transposeW_k<<<dim3(4, 4), 256, 0, stream>>>(edgeW + l * 16384, edgeWT + l * 16384, 128, 128);
    transposeW_k<<<dim3(4, 4), 256, 0, stream>>>(nodeW + l * 16384, nodeWT + l * 16384, 128, 128);
  }
  transposeW_k<<<dim3(16, 4), 256, 0, stream>>>(W1, W1T, 128, 512);
  wfuse_k<<<2, 256, 0, stream>>>(W2, Wdec, wf);
  x0_k<<<dim3(2048, 32), 128, 0, stream>>>(nf, Win, xb, xTb);

  // ---- 3 hypergraph layers, 2 fused dispatches each ----
  for (int l = 0; l < 3; l++) {
    // L1: e = relu((H^T @ x) @ We) -> eT
    gemm_fused<0, 1><<<dim3(512), 256, 0, stream>>>(
        HTb, 2048, 2048L * 2048, 8, xTb, 2048, 128L * 2048,
        edgeWT + l * 16384,
        nullptr, 0, 0, eTb, 2048, 128L * 2048, 2048);
    // L2: x = relu((H @ e) @ Wn) -> xT (+ x on last layer for MLP)
    if (l < 2) {
      gemm_fused<0, 1><<<dim3(512), 256, 0, stream>>>(
          Hb, 2048, 2048L * 2048, 8, eTb, 2048, 128L * 2048,
          nodeWT + l * 16384,
          nullptr, 0, 0, xTb, 2048, 128L * 2048, 2048);
    } else {
      gemm_fused<1, 1><<<dim3(512), 256, 0, stream>>>(
          Hb, 2048, 2048L * 2048, 8, eTb, 2048, 128L * 2048,
          nodeWT + l * 16384,
          xb, 128, 2048L * 128, xTb, 2048, 128L * 2048, 2048);
    }
  }

  // ---- fused MLP + decode ----
  mlp_k<<<dim3(512), 256, 0, stream>>>(xb, W1T, wf, out);
}

// Round 5
// 340.775 us; speedup vs baseline: 1.1970x; 1.1970x over previous
//
#include <hip/hip_runtime.h>
#include <hip/hip_bf16.h>

// HypergraphGNN on MI355X (gfx950).
// B=4 P=8 N=E=2000 IN=16 HID=128 NL=3 MULT=4. All f32 inputs; internal bf16 MFMA.
//
// Round-5 heavy GEMM: BK=64 double-buffer, STATIC unroll (buffer selector is a
// literal), counted s_waitcnt vmcnt(8) (prefetch never drained in main loop),
// 2 ds_read/MFMA phases per K-tile, s_setprio around MFMA clusters, and a
// coalesced transposed C-write via LDS. Addressing is fully hoisted: the LDS
// XOR-swizzle folds to lane-constant chunk offsets (row&7 == fr&7).
//
// LDS swizzle (rule #21): linear LDS dest for global_load_lds; global source
// chunk pre-swizzled; reads apply the same involution.

typedef __attribute__((ext_vector_type(8))) short bf16x8;
typedef __attribute__((ext_vector_type(4))) float f32x4;

#define GLL16(gp, lp) __builtin_amdgcn_global_load_lds(                      \
    (const __attribute__((address_space(1))) void*)(gp),                     \
    (__attribute__((address_space(3))) void*)(lp), 16, 0, 0)

__device__ __forceinline__ unsigned short f2bf(float v) {
  __hip_bfloat16 h = __float2bfloat16(v);
  return __builtin_bit_cast(unsigned short, h);
}
__device__ __forceinline__ float bf2f(unsigned short u) {
  unsigned int x = ((unsigned int)u) << 16;
  return __builtin_bit_cast(float, x);
}

// ---------------------------------------------------------------------------
// H f32 -> Hb (straight) + HTb (transposed), bf16, padded 2000->2048 w/ zeros
__global__ void convH_k(const float* __restrict__ H,
                        unsigned short* __restrict__ Hb,
                        unsigned short* __restrict__ HTb) {
  int b  = blockIdx.z;
  int n0 = blockIdx.y * 32, e0 = blockIdx.x * 32;
  __shared__ float t[32][33];
  int tx = threadIdx.x & 31, ty = threadIdx.x >> 5;
  for (int r = ty; r < 32; r += 8) {
    int n = n0 + r, e = e0 + tx;
    float v = (n < 2000 && e < 2000) ? H[((long)b * 2000 + n) * 2000 + e] : 0.f;
    t[r][tx] = v;
    Hb[((long)b * 2048 + n) * 2048 + e] = f2bf(v);
  }
  __syncthreads();
  for (int r = ty; r < 32; r += 8) {
    HTb[((long)b * 2048 + (e0 + r)) * 2048 + (n0 + tx)] = f2bf(t[tx][r]);
  }
}

// generic f32 [R][C] -> bf16 [C][R]
__global__ void transposeW_k(const float* __restrict__ src,
                             unsigned short* __restrict__ dst, int R, int C) {
  __shared__ float t[32][33];
  int c0 = blockIdx.x * 32, r0 = blockIdx.y * 32;
  int tx = threadIdx.x & 31, ty = threadIdx.x >> 5;
  for (int rr = ty; rr < 32; rr += 8) {
    int rI = r0 + rr, cI = c0 + tx;
    t[rr][tx] = (rI < R && cI < C) ? src[(long)rI * C + cI] : 0.f;
  }
  __syncthreads();
  for (int rr = ty; rr < 32; rr += 8) {
    int cO = c0 + rr, rO = r0 + tx;
    if (cO < C && rO < R) dst[(long)cO * R + rO] = f2bf(t[tx][rr]);
  }
}

// x0 = nf @ W_in  (K=16). Writes xb [bp][2048][128] and xTb [bp][128][2048].
__global__ void x0_k(const float* __restrict__ nf, const float* __restrict__ Win,
                     unsigned short* __restrict__ xb, unsigned short* __restrict__ xTb) {
  int bp = blockIdx.y, n = blockIdx.x, d = threadIdx.x;
  float v = 0.f;
  if (n < 2000) {
    const float* row = nf + ((long)bp * 2000 + n) * 16;
#pragma unroll
    for (int k = 0; k < 16; k++) v += row[k] * Win[k * 128 + d];
  }
  unsigned short bits = f2bf(v);
  xb[((long)bp * 2048 + n) * 128 + d]  = bits;
  xTb[((long)bp * 128 + d) * 2048 + n] = bits;
}

// wf = W2 @ Wdec  (512x128 @ 128 -> 512)
__global__ void wfuse_k(const float* __restrict__ W2, const float* __restrict__ Wdec,
                        float* __restrict__ wf) {
  int i = blockIdx.x * 256 + threadIdx.x;
  if (i < 512) {
    float s = 0.f;
#pragma unroll 8
    for (int j = 0; j < 128; j++) s += W2[i * 128 + j] * Wdec[j];
    wf[i] = s;
  }
}

// ---------------------------------------------------------------------------
// Fused heavy GEMM: acc = A[2048][K=2048] @ BT[128][K]^T per (m-block, bz),
// then out = relu(acc @ W), Wt[d_out][d_in] global. Writes Cn and/or Ct.
// Grid: 512 blocks 1-D, XCD-swizzled. 256 threads. K must be mult of 128.
template <int WN, int WT>
__global__ __launch_bounds__(256, 2) void gemm_fused(
    const unsigned short* __restrict__ A, int lda, long strideA, int aDiv,
    const unsigned short* __restrict__ BT, int ldbt, long strideBT,
    const unsigned short* __restrict__ Wt,
    unsigned short* __restrict__ Cn, int ldc, long strideCn,
    unsigned short* __restrict__ Ct, int ldct, long strideCt, int K) {
  // XCD-aware bijective decode: XCD c = wgid&7 owns orig range [c*64, c*64+64)
  int wgid = blockIdx.x;
  int orig = (wgid & 7) * 64 + (wgid >> 3);
  int mblk = orig & 15;
  int bz   = orig >> 4;
  A  += (long)(bz / aDiv) * strideA;
  BT += (long)bz * strideBT;
  int m0 = mblk * 128;

  // 64 KB LDS: dbuf of [A 128x64 | B 128x64] bf16 (32KB each).
  // Gs/GsT (32KB) alias buffer 0 after the main loop.
  __shared__ unsigned short smem[32768];

  int tid  = threadIdx.x;
  int lane = tid & 63;
  int w    = tid >> 6;
  int wr   = w >> 1, wc = w & 1;
  int fr   = lane & 15;   // frag row (A) / col (B,C)
  int fg   = lane >> 4;   // k-chunk (inputs) / row-subgroup (C/D)

  // ---- staging addressing (BK=64: 8 chunks of 16B per row) ----
  // LDS slot linear; global chunk = slot_chunk ^ (row&7).
  int srow   = tid >> 3;                       // 32 rows per issue
  int schunk = ((tid & 7) ^ (srow & 7)) * 8;   // element offset
  const unsigned short* Agp[4];
  const unsigned short* Bgp[4];
#pragma unroll
  for (int i = 0; i < 4; i++) {
    Agp[i] = A + (long)(m0 + i * 32 + srow) * lda + schunk;
    Bgp[i] = BT + (long)(i * 32 + srow) * ldbt + schunk;
  }

#define STAGE(sel, tk) do {                                                  \
    long _k = (long)(tk) * 64;                                               \
    _Pragma("unroll")                                                        \
    for (int i = 0; i < 4; i++)                                              \
      GLL16(Agp[i] + _k, smem + (sel) * 16384 + (i * 256 + tid) * 8);        \
    _Pragma("unroll")                                                        \
    for (int i = 0; i < 4; i++)                                              \
      GLL16(Bgp[i] + _k, smem + (sel) * 16384 + 8192 + (i * 256 + tid) * 8); \
  } while (0)

  f32x4 acc[4][4] = {};
  // swizzled chunk offsets for the two 32-k phases (row&7 == fr&7 for all frags)
  const int cOff0 = (fg ^ (fr & 7)) * 8;
  const int cOff1 = ((4 + fg) ^ (fr & 7)) * 8;

#define PHASE(Asp, Bsp, CO) do {                                             \
    bf16x8 af[4], bv[4];                                                     \
    _Pragma("unroll")                                                        \
    for (int m = 0; m < 4; m++)                                              \
      af[m] = *(const bf16x8*)&(Asp)[(wr * 64 + m * 16 + fr) * 64 + (CO)];   \
    _Pragma("unroll")                                                        \
    for (int n = 0; n < 4; n++)                                              \
      bv[n] = *(const bf16x8*)&(Bsp)[(wc * 64 + n * 16 + fr) * 64 + (CO)];   \
    __builtin_amdgcn_s_setprio(1);                                           \
    _Pragma("unroll")                                                        \
    for (int m = 0; m < 4; m++)                                              \
      _Pragma("unroll")                                                      \
      for (int n = 0; n < 4; n++)                                            \
        acc[m][n] = __builtin_amdgcn_mfma_f32_16x16x32_bf16(af[m], bv[n],    \
                                                            acc[m][n], 0, 0, 0); \
    __builtin_amdgcn_s_setprio(0);                                           \
  } while (0)

#define COMPUTE64(sel) do {                                                  \
    const unsigned short* As_ = smem + (sel) * 16384;                        \
    const unsigned short* Bs_ = As_ + 8192;                                  \
    PHASE(As_, Bs_, cOff0);                                                  \
    PHASE(As_, Bs_, cOff1);                                                  \
  } while (0)

#define VMW(n) asm volatile("s_waitcnt vmcnt(" #n ")" ::: "memory")
#define BARR __builtin_amdgcn_s_barrier()
#define SCH0 __builtin_amdgcn_sched_barrier(0)

  int nt2 = K >> 6;  // 32 tiles of BK=64 (even)

  STAGE(0, 0);
  int t = 0;
  for (; t + 2 < nt2; t += 2) {
    STAGE(1, t + 1);
    VMW(8); BARR; SCH0;   // tile t landed; t+1 in flight
    COMPUTE64(0);
    BARR;                 // buf0 free
    STAGE(0, t + 2);
    VMW(8); BARR; SCH0;   // tile t+1 landed; t+2 in flight
    COMPUTE64(1);
    BARR;                 // buf1 free
  }
  // t == nt2-2: buf0 holds tile nt2-2 (in flight)
  STAGE(1, nt2 - 1);
  VMW(8); BARR; SCH0;
  COMPUTE64(0);
  BARR;
  VMW(0); BARR; SCH0;
  COMPUTE64(1);
#undef STAGE
#undef COMPUTE64
#undef PHASE

  // ---- stage-1 acc -> Gs bf16 row-major 128x128, chunk swizzled ----
  // (buf1 was the last-read staging buffer; Gs aliases buf0, whose last read
  //  completed before the final VMW(0) barrier -> no extra barrier needed.)
  unsigned short* Gs = smem;
#pragma unroll
  for (int m = 0; m < 4; m++) {
#pragma unroll
    for (int n = 0; n < 4; n++) {
      int rowb = wr * 64 + m * 16 + fg * 4;
      int col  = wc * 64 + n * 16 + fr;
      int ch = col >> 3, ci = col & 7;
#pragma unroll
      for (int r = 0; r < 4; r++) {
        int row = rowb + r;
        Gs[row * 128 + ((ch ^ (row & 7)) * 8) + ci] = f2bf(acc[m][n][r]);
      }
    }
  }
  __syncthreads();

  // ---- stage 2: out = relu(G @ W); A-op = Gs, B-op = Wt global (L2-hot) ----
  f32x4 acc2[4][4] = {};
#pragma unroll
  for (int kk = 0; kk < 4; kk++) {
    bf16x8 a2[4], b2[4];
#pragma unroll
    for (int m = 0; m < 4; m++) {
      int row = wr * 64 + m * 16 + fr;
      int c = kk * 4 + fg;
      a2[m] = *(const bf16x8*)&Gs[row * 128 + ((c ^ (fr & 7)) * 8)];
    }
#pragma unroll
    for (int n = 0; n < 4; n++) {
      int row = wc * 64 + n * 16 + fr;
      b2[n] = *(const bf16x8*)&Wt[row * 128 + (kk * 4 + fg) * 8];
    }
#pragma unroll
    for (int m = 0; m < 4; m++)
#pragma unroll
      for (int n = 0; n < 4; n++)
        acc2[m][n] = __builtin_amdgcn_mfma_f32_16x16x32_bf16(a2[m], b2[n], acc2[m][n], 0, 0, 0);
  }

  // optional normal-layout write (one dispatch only), direct from regs
  if (WN) {
#pragma unroll
    for (int m = 0; m < 4; m++) {
#pragma unroll
      for (int n = 0; n < 4; n++) {
        int rowb = m0 + wr * 64 + m * 16 + fg * 4;
        int col  = wc * 64 + n * 16 + fr;
        unsigned short* p = Cn + bz * strideCn + (long)rowb * ldc + col;
        p[0]       = f2bf(fmaxf(acc2[m][n][0], 0.f));
        p[ldc]     = f2bf(fmaxf(acc2[m][n][1], 0.f));
        p[2 * ldc] = f2bf(fmaxf(acc2[m][n][2], 0.f));
        p[3 * ldc] = f2bf(fmaxf(acc2[m][n][3], 0.f));
      }
    }
  }

  if (WT) {
    // relu'd acc2 -> GsT [col][128 rows] bf16 (chunk swizzled), then
    // coalesced 16B stores: Ct row = col, 256B contiguous per 16 lanes.
    __syncthreads();  // all Gs reads done before overwrite
    unsigned short* GsT = smem;
#pragma unroll
    for (int m = 0; m < 4; m++) {
#pragma unroll
      for (int n = 0; n < 4; n++) {
        int rowb = wr * 64 + m * 16 + fg * 4;   // rowb&7 = (fg&1)*4
        int col  = wc * 64 + n * 16 + fr;
        int chunk = rowb >> 3;
        ushort4 pk;
        pk.x = f2bf(fmaxf(acc2[m][n][0], 0.f));
        pk.y = f2bf(fmaxf(acc2[m][n][1], 0.f));
        pk.z = f2bf(fmaxf(acc2[m][n][2], 0.f));
        pk.w = f2bf(fmaxf(acc2[m][n][3], 0.f));
        *(ushort4*)&GsT[col * 128 + ((chunk ^ (col & 7)) * 8) + (rowb & 7)] = pk;
      }
    }
    __syncthreads();
    unsigned short* CtB = Ct + bz * strideCt + m0;
#pragma unroll
    for (int i = 0; i < 8; i++) {
      int s = i * 256 + tid;
      int col = s >> 4, slot = s & 15;
      int l = slot ^ (col & 7);  // logical row-chunk
      bf16x8 v = *(const bf16x8*)&GsT[col * 128 + slot * 8];
      *(bf16x8*)(CtB + (long)col * ldct + l * 8) = v;
    }
  }
}

// ---------------------------------------------------------------------------
// Fused MLP: out[row] = 10*tanh( (sum_i relu(x@W1)[row][i]*wf[i]) / sqrt(128) )
__global__ __launch_bounds__(256) void mlp_k(
    const unsigned short* __restrict__ X,    // [65536][128] bf16 (padded rows)
    const unsigned short* __restrict__ W1T,  // [512][128] bf16
    const float* __restrict__ wf,            // [512]
    float* __restrict__ out) {
  __shared__ unsigned short Xs[128 * 128];
  __shared__ unsigned short Bs[128 * 128];
  __shared__ float rowacc[128];

  int tid  = threadIdx.x;
  int lane = tid & 63;
  int w    = tid >> 6, wr = w >> 1, wc = w & 1;
  int fr   = lane & 15, fg = lane >> 4;
  long m0  = (long)blockIdx.x * 128;

#pragma unroll
  for (int i = 0; i < 8; i++) {
    int s = i * 256 + tid;
    int r = s >> 4, c = (s & 15) ^ (r & 7);
    GLL16(X + (m0 + r) * 128 + c * 8, (unsigned short*)Xs + s * 8);
  }
  if (tid < 128) rowacc[tid] = 0.f;

  float rs[4][4] = {};

  for (int nb = 0; nb < 4; nb++) {
#pragma unroll
    for (int i = 0; i < 8; i++) {
      int s = i * 256 + tid;
      int r = s >> 4, c = (s & 15) ^ (r & 7);
      GLL16(W1T + (long)(nb * 128 + r) * 128 + c * 8, (unsigned short*)Bs + s * 8);
    }
    __syncthreads();

    f32x4 acc[4][4] = {};
#pragma unroll
    for (int kk = 0; kk < 4; kk++) {
      bf16x8 a2[4], b2[4];
#pragma unroll
      for (int m = 0; m < 4; m++) {
        int row = wr * 64 + m * 16 + fr;
        int c = kk * 4 + fg;
        a2[m] = *(const bf16x8*)&Xs[row * 128 + ((c ^ (row & 7)) * 8)];
      }
#pragma unroll
      for (int n = 0; n < 4; n++) {
        int row = wc * 64 + n * 16 + fr;
        int c = kk * 4 + fg;
        b2[n] = *(const bf16x8*)&Bs[row * 128 + ((c ^ (row & 7)) * 8)];
      }
#pragma unroll
      for (int m = 0; m < 4; m++)
#pragma unroll
        for (int n = 0; n < 4; n++)
          acc[m][n] = __builtin_amdgcn_mfma_f32_16x16x32_bf16(a2[m], b2[n], acc[m][n], 0, 0, 0);
    }

#pragma unroll
    for (int n = 0; n < 4; n++) {
      float wv = wf[nb * 128 + wc * 64 + n * 16 + fr];
#pragma unroll
      for (int m = 0; m < 4; m++)
#pragma unroll
        for (int r = 0; r < 4; r++)
          rs[m][r] += fmaxf(acc[m][n][r], 0.f) * wv;
    }
    __syncthreads();
  }

#pragma unroll
  for (int m = 0; m < 4; m++)
#pragma unroll
    for (int r = 0; r < 4; r++) {
      float v = rs[m][r];
      v += __shfl_xor(v, 1, 64);
      v += __shfl_xor(v, 2, 64);
      v += __shfl_xor(v, 4, 64);
      v += __shfl_xor(v, 8, 64);
      if (fr == 0) atomicAdd(&rowacc[wr * 64 + m * 16 + fg * 4 + r], v);
    }
  __syncthreads();

  if (tid < 128) {
    long row = m0 + tid;
    int bp = (int)(row >> 11), n = (int)(row & 2047);
    if (n < 2000)
      out[(long)bp * 2000 + n] = 10.f * tanhf(rowacc[tid] * 0.08838834764831843f);
  }
}

// ---------------------------------------------------------------------------
extern "C" void kernel_launch(void* const* d_in, const int* in_sizes, int n_in,
                              void* d_out, int out_size, void* d_ws, size_t ws_size,
                              hipStream_t stream) {
  const float* nf    = (const float*)d_in[0];
  const float* H     = (const float*)d_in[1];
  const float* Win   = (const float*)d_in[2];
  const float* edgeW = (const float*)d_in[3];
  const float* nodeW = (const float*)d_in[4];
  const float* W1    = (const float*)d_in[5];
  const float* W2    = (const float*)d_in[6];
  const float* Wdec  = (const float*)d_in[7];
  float* out = (float*)d_out;

  char* ws = (char*)d_ws;
  unsigned short* Hb   = (unsigned short*)(ws + 0);          // 33.55 MB
  unsigned short* HTb  = (unsigned short*)(ws + 33554432);   // 33.55 MB
  unsigned short* xb   = (unsigned short*)(ws + 67108864);   // 16.78 MB
  unsigned short* xTb  = (unsigned short*)(ws + 83886080);   // 16.78 MB
  unsigned short* eTb  = (unsigned short*)(ws + 100663296);  // 16.78 MB
  unsigned short* edgeWT = (unsigned short*)(ws + 117440512);
  unsigned short* nodeWT = (unsigned short*)(ws + 117538816);
  unsigned short* W1T    = (unsigned short*)(ws + 117637120);
  float*          wf     = (float*)(ws + 117768192);
  (void)ws_size; (void)in_sizes; (void)n_in; (void)out_size;

  // ---- input prep ----
  convH_k<<<dim3(64, 64, 4), 256, 0, stream>>>(H, Hb, HTb);
  for (int l = 0; l < 3; l++) {
    transposeW_k<<<dim3(4, 4), 256, 0, stream>>>(edgeW + l * 16384, edgeWT + l * 16384, 128, 128);
    transposeW_k<<<dim3(4, 4), 256, 0, stream>>>(nodeW + l * 16384, nodeWT + l * 16384, 128, 128);
  }
  transposeW_k<<<dim3(16, 4), 256, 0, stream>>>(W1, W1T, 128, 512);
  wfuse_k<<<2, 256, 0, stream>>>(W2, Wdec, wf);
  x0_k<<<dim3(2048, 32), 128, 0, stream>>>(nf, Win, xb, xTb);

  // ---- 3 hypergraph layers, 2 fused dispatches each ----
  for (int l = 0; l < 3; l++) {
    // L1: e = relu((H^T @ x) @ We) -> eT
    gemm_fused<0, 1><<<dim3(512), 256, 0, stream>>>(
        HTb, 2048, 2048L * 2048, 8, xTb, 2048, 128L * 2048,
        edgeWT + l * 16384,
        nullptr, 0, 0, eTb, 2048, 128L * 2048, 2048);
    // L2: x = relu((H @ e) @ Wn) -> xT (+ x on last layer for MLP)
    if (l < 2) {
      gemm_fused<0, 1><<<dim3(512), 256, 0, stream>>>(
          Hb, 2048, 2048L * 2048, 8, eTb, 2048, 128L * 2048,
          nodeWT + l * 16384,
          nullptr, 0, 0, xTb, 2048, 128L * 2048, 2048);
    } else {
      gemm_fused<1, 1><<<dim3(512), 256, 0, stream>>>(
          Hb, 2048, 2048L * 2048, 8, eTb, 2048, 128L * 2048,
          nodeWT + l * 16384,
          xb, 128, 2048L * 128, xTb, 2048, 128L * 2048, 2048);
    }
  }

  // ---- fused MLP + decode ----
  mlp_k<<<dim3(512), 256, 0, stream>>>(xb, W1T, wf, out);
}

// Round 6
// 313.803 us; speedup vs baseline: 1.2999x; 1.0860x over previous
//
#include <hip/hip_runtime.h>
#include <hip/hip_bf16.h>

// HypergraphGNN on MI355X (gfx950).
// B=4 P=8 N=E=2000 IN=16 HID=128 NL=3 MULT=4. All f32 inputs; internal bf16 MFMA.
//
// Round-6: x0_k rewritten to kill transposed-write sector amplification
// (54.7us, 147MB written -> ~10us, 34MB): thread owns one d-column, its 64
// values are contiguous in xT layout (8x16B sector-complete stores); xb is
// emitted via a padded LDS tile, coalesced row-major.
// Heavy GEMM unchanged from round 5 (BK=64 static dbuf, counted vmcnt(8),
// setprio-wrapped MFMA phases, coalesced WT write via LDS).

typedef __attribute__((ext_vector_type(8))) short bf16x8;
typedef __attribute__((ext_vector_type(4))) float f32x4;

#define GLL16(gp, lp) __builtin_amdgcn_global_load_lds(                      \
    (const __attribute__((address_space(1))) void*)(gp),                     \
    (__attribute__((address_space(3))) void*)(lp), 16, 0, 0)

__device__ __forceinline__ unsigned short f2bf(float v) {
  __hip_bfloat16 h = __float2bfloat16(v);
  return __builtin_bit_cast(unsigned short, h);
}
__device__ __forceinline__ float bf2f(unsigned short u) {
  unsigned int x = ((unsigned int)u) << 16;
  return __builtin_bit_cast(float, x);
}

// ---------------------------------------------------------------------------
// H f32 -> Hb (straight) + HTb (transposed), bf16, padded 2000->2048 w/ zeros
__global__ void convH_k(const float* __restrict__ H,
                        unsigned short* __restrict__ Hb,
                        unsigned short* __restrict__ HTb) {
  int b  = blockIdx.z;
  int n0 = blockIdx.y * 32, e0 = blockIdx.x * 32;
  __shared__ float t[32][33];
  int tx = threadIdx.x & 31, ty = threadIdx.x >> 5;
  for (int r = ty; r < 32; r += 8) {
    int n = n0 + r, e = e0 + tx;
    float v = (n < 2000 && e < 2000) ? H[((long)b * 2000 + n) * 2000 + e] : 0.f;
    t[r][tx] = v;
    Hb[((long)b * 2048 + n) * 2048 + e] = f2bf(v);
  }
  __syncthreads();
  for (int r = ty; r < 32; r += 8) {
    HTb[((long)b * 2048 + (e0 + r)) * 2048 + (n0 + tx)] = f2bf(t[tx][r]);
  }
}

// generic f32 [R][C] -> bf16 [C][R]
__global__ void transposeW_k(const float* __restrict__ src,
                             unsigned short* __restrict__ dst, int R, int C) {
  __shared__ float t[32][33];
  int c0 = blockIdx.x * 32, r0 = blockIdx.y * 32;
  int tx = threadIdx.x & 31, ty = threadIdx.x >> 5;
  for (int rr = ty; rr < 32; rr += 8) {
    int rI = r0 + rr, cI = c0 + tx;
    t[rr][tx] = (rI < R && cI < C) ? src[(long)rI * C + cI] : 0.f;
  }
  __syncthreads();
  for (int rr = ty; rr < 32; rr += 8) {
    int cO = c0 + rr, rO = r0 + tx;
    if (cO < C && rO < R) dst[(long)cO * R + rO] = f2bf(t[tx][rr]);
  }
}

// x0 = nf @ W_in (K=16). Tile: 128 nodes x 128 dims per block.
// Thread t owns column d = t&127, half = t>>7 (64 nodes). Its 64 values are
// contiguous in xT layout -> 8x16B sector-complete stores. xb goes through a
// padded LDS tile for coalesced row-major emission.
__global__ __launch_bounds__(256) void x0_k(
    const float* __restrict__ nf, const float* __restrict__ Win,
    unsigned short* __restrict__ xb, unsigned short* __restrict__ xTb) {
  __shared__ float nfs[128][16];         // 8 KB
  __shared__ float wins[2048];           // 8 KB ([16][128] flat, same as Win)
  __shared__ unsigned short xt[128][136]; // 34 KB (pad 8: 272B row, 16B-aligned)

  int bp = blockIdx.y;
  int n0 = blockIdx.x * 128;
  int tid = threadIdx.x;

  // stage nf rows (2 threads per row, 32B each)
  {
    int r = tid >> 1, c = (tid & 1) * 8;
    int n = n0 + r;
    float4 v0 = make_float4(0.f, 0.f, 0.f, 0.f), v1 = v0;
    if (n < 2000) {
      const float* src = nf + ((long)bp * 2000 + n) * 16 + c;
      v0 = *(const float4*)src;
      v1 = *(const float4*)(src + 4);
    }
    *(float4*)&nfs[r][c]     = v0;
    *(float4*)&nfs[r][c + 4] = v1;
  }
  // stage Win (8 floats per thread)
  {
    int base = tid * 8;
    float4 a = *(const float4*)(Win + base);
    float4 b = *(const float4*)(Win + base + 4);
    *(float4*)&wins[base]     = a;
    *(float4*)&wins[base + 4] = b;
  }
  __syncthreads();

  int d = tid & 127, half = tid >> 7;
  float wcol[16];
#pragma unroll
  for (int k = 0; k < 16; k++) wcol[k] = wins[k * 128 + d];

  unsigned short* xtRow = xTb + ((long)bp * 128 + d) * 2048 + n0 + half * 64;
#pragma unroll
  for (int oct = 0; oct < 8; oct++) {
    bf16x8 pk;
#pragma unroll
    for (int j = 0; j < 8; j++) {
      int nl = half * 64 + oct * 8 + j;
      float v = 0.f;
#pragma unroll
      for (int k = 0; k < 16; k++) v += nfs[nl][k] * wcol[k];
      unsigned short bits = f2bf(v);
      pk[j] = (short)bits;
      xt[nl][d] = bits;
    }
    *(bf16x8*)(xtRow + oct * 8) = pk;  // 16B contiguous, sector-complete
  }
  __syncthreads();

  // xb emission: thread t reads row r = t>>1, half c0 = (t&1)*64 from LDS,
  // writes 128B contiguous (full rows coalesced across threads).
  {
    int r = tid >> 1, c0 = (tid & 1) * 64;
    unsigned short* dst = xb + ((long)bp * 2048 + n0 + r) * 128 + c0;
#pragma unroll
    for (int i = 0; i < 8; i++) {
      bf16x8 v = *(const bf16x8*)&xt[r][c0 + i * 8];
      *(bf16x8*)(dst + i * 8) = v;
    }
  }
}

// wf = W2 @ Wdec  (512x128 @ 128 -> 512)
__global__ void wfuse_k(const float* __restrict__ W2, const float* __restrict__ Wdec,
                        float* __restrict__ wf) {
  int i = blockIdx.x * 256 + threadIdx.x;
  if (i < 512) {
    float s = 0.f;
#pragma unroll 8
    for (int j = 0; j < 128; j++) s += W2[i * 128 + j] * Wdec[j];
    wf[i] = s;
  }
}

// ---------------------------------------------------------------------------
// Fused heavy GEMM: acc = A[2048][K=2048] @ BT[128][K]^T per (m-block, bz),
// then out = relu(acc @ W), Wt[d_out][d_in] global. Writes Cn and/or Ct.
// Grid: 512 blocks 1-D, XCD-swizzled. 256 threads. K must be mult of 128.
template <int WN, int WT>
__global__ __launch_bounds__(256, 2) void gemm_fused(
    const unsigned short* __restrict__ A, int lda, long strideA, int aDiv,
    const unsigned short* __restrict__ BT, int ldbt, long strideBT,
    const unsigned short* __restrict__ Wt,
    unsigned short* __restrict__ Cn, int ldc, long strideCn,
    unsigned short* __restrict__ Ct, int ldct, long strideCt, int K) {
  // XCD-aware bijective decode: XCD c = wgid&7 owns orig range [c*64, c*64+64)
  int wgid = blockIdx.x;
  int orig = (wgid & 7) * 64 + (wgid >> 3);
  int mblk = orig & 15;
  int bz   = orig >> 4;
  A  += (long)(bz / aDiv) * strideA;
  BT += (long)bz * strideBT;
  int m0 = mblk * 128;

  // 64 KB LDS: dbuf of [A 128x64 | B 128x64] bf16 (32KB each).
  // Gs/GsT (32KB) alias buffer 0 after the main loop.
  __shared__ unsigned short smem[32768];

  int tid  = threadIdx.x;
  int lane = tid & 63;
  int w    = tid >> 6;
  int wr   = w >> 1, wc = w & 1;
  int fr   = lane & 15;   // frag row (A) / col (B,C)
  int fg   = lane >> 4;   // k-chunk (inputs) / row-subgroup (C/D)

  // ---- staging addressing (BK=64: 8 chunks of 16B per row) ----
  // LDS slot linear; global chunk = slot_chunk ^ (row&7).
  int srow   = tid >> 3;                       // 32 rows per issue
  int schunk = ((tid & 7) ^ (srow & 7)) * 8;   // element offset
  const unsigned short* Agp[4];
  const unsigned short* Bgp[4];
#pragma unroll
  for (int i = 0; i < 4; i++) {
    Agp[i] = A + (long)(m0 + i * 32 + srow) * lda + schunk;
    Bgp[i] = BT + (long)(i * 32 + srow) * ldbt + schunk;
  }

#define STAGE(sel, tk) do {                                                  \
    long _k = (long)(tk) * 64;                                               \
    _Pragma("unroll")                                                        \
    for (int i = 0; i < 4; i++)                                              \
      GLL16(Agp[i] + _k, smem + (sel) * 16384 + (i * 256 + tid) * 8);        \
    _Pragma("unroll")                                                        \
    for (int i = 0; i < 4; i++)                                              \
      GLL16(Bgp[i] + _k, smem + (sel) * 16384 + 8192 + (i * 256 + tid) * 8); \
  } while (0)

  f32x4 acc[4][4] = {};
  // swizzled chunk offsets for the two 32-k phases (row&7 == fr&7 for all frags)
  const int cOff0 = (fg ^ (fr & 7)) * 8;
  const int cOff1 = ((4 + fg) ^ (fr & 7)) * 8;

#define PHASE(Asp, Bsp, CO) do {                                             \
    bf16x8 af[4], bv[4];                                                     \
    _Pragma("unroll")                                                        \
    for (int m = 0; m < 4; m++)                                              \
      af[m] = *(const bf16x8*)&(Asp)[(wr * 64 + m * 16 + fr) * 64 + (CO)];   \
    _Pragma("unroll")                                                        \
    for (int n = 0; n < 4; n++)                                              \
      bv[n] = *(const bf16x8*)&(Bsp)[(wc * 64 + n * 16 + fr) * 64 + (CO)];   \
    __builtin_amdgcn_s_setprio(1);                                           \
    _Pragma("unroll")                                                        \
    for (int m = 0; m < 4; m++)                                              \
      _Pragma("unroll")                                                      \
      for (int n = 0; n < 4; n++)                                            \
        acc[m][n] = __builtin_amdgcn_mfma_f32_16x16x32_bf16(af[m], bv[n],    \
                                                            acc[m][n], 0, 0, 0); \
    __builtin_amdgcn_s_setprio(0);                                           \
  } while (0)

#define COMPUTE64(sel) do {                                                  \
    const unsigned short* As_ = smem + (sel) * 16384;                        \
    const unsigned short* Bs_ = As_ + 8192;                                  \
    PHASE(As_, Bs_, cOff0);                                                  \
    PHASE(As_, Bs_, cOff1);                                                  \
  } while (0)

#define VMW(n) asm volatile("s_waitcnt vmcnt(" #n ")" ::: "memory")
#define BARR __builtin_amdgcn_s_barrier()
#define SCH0 __builtin_amdgcn_sched_barrier(0)

  int nt2 = K >> 6;  // 32 tiles of BK=64 (even)

  STAGE(0, 0);
  int t = 0;
  for (; t + 2 < nt2; t += 2) {
    STAGE(1, t + 1);
    VMW(8); BARR; SCH0;   // tile t landed; t+1 in flight
    COMPUTE64(0);
    BARR;                 // buf0 free
    STAGE(0, t + 2);
    VMW(8); BARR; SCH0;   // tile t+1 landed; t+2 in flight
    COMPUTE64(1);
    BARR;                 // buf1 free
  }
  // t == nt2-2: buf0 holds tile nt2-2 (in flight)
  STAGE(1, nt2 - 1);
  VMW(8); BARR; SCH0;
  COMPUTE64(0);
  BARR;
  VMW(0); BARR; SCH0;
  COMPUTE64(1);
#undef STAGE
#undef COMPUTE64
#undef PHASE

  // ---- stage-1 acc -> Gs bf16 row-major 128x128, chunk swizzled ----
  unsigned short* Gs = smem;
#pragma unroll
  for (int m = 0; m < 4; m++) {
#pragma unroll
    for (int n = 0; n < 4; n++) {
      int rowb = wr * 64 + m * 16 + fg * 4;
      int col  = wc * 64 + n * 16 + fr;
      int ch = col >> 3, ci = col & 7;
#pragma unroll
      for (int r = 0; r < 4; r++) {
        int row = rowb + r;
        Gs[row * 128 + ((ch ^ (row & 7)) * 8) + ci] = f2bf(acc[m][n][r]);
      }
    }
  }
  __syncthreads();

  // ---- stage 2: out = relu(G @ W); A-op = Gs, B-op = Wt global (L2-hot) ----
  f32x4 acc2[4][4] = {};
#pragma unroll
  for (int kk = 0; kk < 4; kk++) {
    bf16x8 a2[4], b2[4];
#pragma unroll
    for (int m = 0; m < 4; m++) {
      int row = wr * 64 + m * 16 + fr;
      int c = kk * 4 + fg;
      a2[m] = *(const bf16x8*)&Gs[row * 128 + ((c ^ (fr & 7)) * 8)];
    }
#pragma unroll
    for (int n = 0; n < 4; n++) {
      int row = wc * 64 + n * 16 + fr;
      b2[n] = *(const bf16x8*)&Wt[row * 128 + (kk * 4 + fg) * 8];
    }
#pragma unroll
    for (int m = 0; m < 4; m++)
#pragma unroll
      for (int n = 0; n < 4; n++)
        acc2[m][n] = __builtin_amdgcn_mfma_f32_16x16x32_bf16(a2[m], b2[n], acc2[m][n], 0, 0, 0);
  }

  // optional normal-layout write (one dispatch only), direct from regs
  if (WN) {
#pragma unroll
    for (int m = 0; m < 4; m++) {
#pragma unroll
      for (int n = 0; n < 4; n++) {
        int rowb = m0 + wr * 64 + m * 16 + fg * 4;
        int col  = wc * 64 + n * 16 + fr;
        unsigned short* p = Cn + bz * strideCn + (long)rowb * ldc + col;
        p[0]       = f2bf(fmaxf(acc2[m][n][0], 0.f));
        p[ldc]     = f2bf(fmaxf(acc2[m][n][1], 0.f));
        p[2 * ldc] = f2bf(fmaxf(acc2[m][n][2], 0.f));
        p[3 * ldc] = f2bf(fmaxf(acc2[m][n][3], 0.f));
      }
    }
  }

  if (WT) {
    // relu'd acc2 -> GsT [col][128 rows] bf16 (chunk swizzled), then
    // coalesced 16B stores: Ct row = col, 256B contiguous per 16 lanes.
    __syncthreads();  // all Gs reads done before overwrite
    unsigned short* GsT = smem;
#pragma unroll
    for (int m = 0; m < 4; m++) {
#pragma unroll
      for (int n = 0; n < 4; n++) {
        int rowb = wr * 64 + m * 16 + fg * 4;   // rowb&7 = (fg&1)*4
        int col  = wc * 64 + n * 16 + fr;
        int chunk = rowb >> 3;
        ushort4 pk;
        pk.x = f2bf(fmaxf(acc2[m][n][0], 0.f));
        pk.y = f2bf(fmaxf(acc2[m][n][1], 0.f));
        pk.z = f2bf(fmaxf(acc2[m][n][2], 0.f));
        pk.w = f2bf(fmaxf(acc2[m][n][3], 0.f));
        *(ushort4*)&GsT[col * 128 + ((chunk ^ (col & 7)) * 8) + (rowb & 7)] = pk;
      }
    }
    __syncthreads();
    unsigned short* CtB = Ct + bz * strideCt + m0;
#pragma unroll
    for (int i = 0; i < 8; i++) {
      int s = i * 256 + tid;
      int col = s >> 4, slot = s & 15;
      int l = slot ^ (col & 7);  // logical row-chunk
      bf16x8 v = *(const bf16x8*)&GsT[col * 128 + slot * 8];
      *(bf16x8*)(CtB + (long)col * ldct + l * 8) = v;
    }
  }
}

// ---------------------------------------------------------------------------
// Fused MLP: out[row] = 10*tanh( (sum_i relu(x@W1)[row][i]*wf[i]) / sqrt(128) )
__global__ __launch_bounds__(256) void mlp_k(
    const unsigned short* __restrict__ X,    // [65536][128] bf16 (padded rows)
    const unsigned short* __restrict__ W1T,  // [512][128] bf16
    const float* __restrict__ wf,            // [512]
    float* __restrict__ out) {
  __shared__ unsigned short Xs[128 * 128];
  __shared__ unsigned short Bs[128 * 128];
  __shared__ float rowacc[128];

  int tid  = threadIdx.x;
  int lane = tid & 63;
  int w    = tid >> 6, wr = w >> 1, wc = w & 1;
  int fr   = lane & 15, fg = lane >> 4;
  long m0  = (long)blockIdx.x * 128;

#pragma unroll
  for (int i = 0; i < 8; i++) {
    int s = i * 256 + tid;
    int r = s >> 4, c = (s & 15) ^ (r & 7);
    GLL16(X + (m0 + r) * 128 + c * 8, (unsigned short*)Xs + s * 8);
  }
  if (tid < 128) rowacc[tid] = 0.f;

  float rs[4][4] = {};

  for (int nb = 0; nb < 4; nb++) {
#pragma unroll
    for (int i = 0; i < 8; i++) {
      int s = i * 256 + tid;
      int r = s >> 4, c = (s & 15) ^ (r & 7);
      GLL16(W1T + (long)(nb * 128 + r) * 128 + c * 8, (unsigned short*)Bs + s * 8);
    }
    __syncthreads();

    f32x4 acc[4][4] = {};
#pragma unroll
    for (int kk = 0; kk < 4; kk++) {
      bf16x8 a2[4], b2[4];
#pragma unroll
      for (int m = 0; m < 4; m++) {
        int row = wr * 64 + m * 16 + fr;
        int c = kk * 4 + fg;
        a2[m] = *(const bf16x8*)&Xs[row * 128 + ((c ^ (row & 7)) * 8)];
      }
#pragma unroll
      for (int n = 0; n < 4; n++) {
        int row = wc * 64 + n * 16 + fr;
        int c = kk * 4 + fg;
        b2[n] = *(const bf16x8*)&Bs[row * 128 + ((c ^ (row & 7)) * 8)];
      }
#pragma unroll
      for (int m = 0; m < 4; m++)
#pragma unroll
        for (int n = 0; n < 4; n++)
          acc[m][n] = __builtin_amdgcn_mfma_f32_16x16x32_bf16(a2[m], b2[n], acc[m][n], 0, 0, 0);
    }

#pragma unroll
    for (int n = 0; n < 4; n++) {
      float wv = wf[nb * 128 + wc * 64 + n * 16 + fr];
#pragma unroll
      for (int m = 0; m < 4; m++)
#pragma unroll
        for (int r = 0; r < 4; r++)
          rs[m][r] += fmaxf(acc[m][n][r], 0.f) * wv;
    }
    __syncthreads();
  }

#pragma unroll
  for (int m = 0; m < 4; m++)
#pragma unroll
    for (int r = 0; r < 4; r++) {
      float v = rs[m][r];
      v += __shfl_xor(v, 1, 64);
      v += __shfl_xor(v, 2, 64);
      v += __shfl_xor(v, 4, 64);
      v += __shfl_xor(v, 8, 64);
      if (fr == 0) atomicAdd(&rowacc[wr * 64 + m * 16 + fg * 4 + r], v);
    }
  __syncthreads();

  if (tid < 128) {
    long row = m0 + tid;
    int bp = (int)(row >> 11), n = (int)(row & 2047);
    if (n < 2000)
      out[(long)bp * 2000 + n] = 10.f * tanhf(rowacc[tid] * 0.08838834764831843f);
  }
}

// ---------------------------------------------------------------------------
extern "C" void kernel_launch(void* const* d_in, const int* in_sizes, int n_in,
                              void* d_out, int out_size, void* d_ws, size_t ws_size,
                              hipStream_t stream) {
  const float* nf    = (const float*)d_in[0];
  const float* H     = (const float*)d_in[1];
  const float* Win   = (const float*)d_in[2];
  const float* edgeW = (const float*)d_in[3];
  const float* nodeW = (const float*)d_in[4];
  const float* W1    = (const float*)d_in[5];
  const float* W2    = (const float*)d_in[6];
  const float* Wdec  = (const float*)d_in[7];
  float* out = (float*)d_out;

  char* ws = (char*)d_ws;
  unsigned short* Hb   = (unsigned short*)(ws + 0);          // 33.55 MB
  unsigned short* HTb  = (unsigned short*)(ws + 33554432);   // 33.55 MB
  unsigned short* xb   = (unsigned short*)(ws + 67108864);   // 16.78 MB
  unsigned short* xTb  = (unsigned short*)(ws + 83886080);   // 16.78 MB
  unsigned short* eTb  = (unsigned short*)(ws + 100663296);  // 16.78 MB
  unsigned short* edgeWT = (unsigned short*)(ws + 117440512);
  unsigned short* nodeWT = (unsigned short*)(ws + 117538816);
  unsigned short* W1T    = (unsigned short*)(ws + 117637120);
  float*          wf     = (float*)(ws + 117768192);
  (void)ws_size; (void)in_sizes; (void)n_in; (void)out_size;

  // ---- input prep ----
  convH_k<<<dim3(64, 64, 4), 256, 0, stream>>>(H, Hb, HTb);
  for (int l = 0; l < 3; l++) {
    transposeW_k<<<dim3(4, 4), 256, 0, stream>>>(edgeW + l * 16384, edgeWT + l * 16384, 128, 128);
    transposeW_k<<<dim3(4, 4), 256, 0, stream>>>(nodeW + l * 16384, nodeWT + l * 16384, 128, 128);
  }
  transposeW_k<<<dim3(16, 4), 256, 0, stream>>>(W1, W1T, 128, 512);
  wfuse_k<<<2, 256, 0, stream>>>(W2, Wdec, wf);
  x0_k<<<dim3(16, 32), 256, 0, stream>>>(nf, Win, xb, xTb);

  // ---- 3 hypergraph layers, 2 fused dispatches each ----
  for (int l = 0; l < 3; l++) {
    // L1: e = relu((H^T @ x) @ We) -> eT
    gemm_fused<0, 1><<<dim3(512), 256, 0, stream>>>(
        HTb, 2048, 2048L * 2048, 8, xTb, 2048, 128L * 2048,
        edgeWT + l * 16384,
        nullptr, 0, 0, eTb, 2048, 128L * 2048, 2048);
    // L2: x = relu((H @ e) @ Wn) -> xT (+ x on last layer for MLP)
    if (l < 2) {
      gemm_fused<0, 1><<<dim3(512), 256, 0, stream>>>(
          Hb, 2048, 2048L * 2048, 8, eTb, 2048, 128L * 2048,
          nodeWT + l * 16384,
          nullptr, 0, 0, xTb, 2048, 128L * 2048, 2048);
    } else {
      gemm_fused<1, 1><<<dim3(512), 256, 0, stream>>>(
          Hb, 2048, 2048L * 2048, 8, eTb, 2048, 128L * 2048,
          nodeWT + l * 16384,
          xb, 128, 2048L * 128, xTb, 2048, 128L * 2048, 2048);
    }
  }

  // ---- fused MLP + decode ----
  mlp_k<<<dim3(512), 256, 0, stream>>>(xb, W1T, wf, out);
}